// Round 15
// baseline (181.308 us; speedup 1.0000x reference)
//
#include <hip/hip_runtime.h>
#include <cstdint>
#include <cstddef>

// ---------------------------------------------------------------------------
// Types / helpers
// ---------------------------------------------------------------------------
typedef __bf16 bf16x8 __attribute__((ext_vector_type(8)));
typedef float f32x4 __attribute__((ext_vector_type(4)));
typedef unsigned short u16x8 __attribute__((ext_vector_type(8)));
typedef unsigned int u32x4 __attribute__((ext_vector_type(4)));

#define AS1 __attribute__((address_space(1)))
#define AS3 __attribute__((address_space(3)))

__device__ __forceinline__ void gload16(const void* g, void* l) {
    // async global->LDS, 16B per lane; LDS dest = wave-uniform base + lane*16
    __builtin_amdgcn_global_load_lds((AS1 unsigned int*)(unsigned long long)g,
                                     (AS3 unsigned int*)l, 16, 0, 0);
}

__device__ __forceinline__ unsigned short f2b(float f) {  // f32 -> bf16 RNE
    unsigned u = __builtin_bit_cast(unsigned, f);
    return (unsigned short)((u + 0x7fffu + ((u >> 16) & 1u)) >> 16);
}
__device__ __forceinline__ float b2f(unsigned short h) {
    return __builtin_bit_cast(float, ((unsigned)h) << 16);
}

static constexpr int HW = 16384;

// ---------------------------------------------------------------------------
// zero borders of 9 padded NHWC buffers (X*: C=64, F*/G*: C=128)
// ---------------------------------------------------------------------------
__global__ __launch_bounds__(256) void zero_borders_kernel(
    unsigned short* X0, unsigned short* X1, unsigned short* X2,
    unsigned short* F0, unsigned short* F1, unsigned short* F2,
    unsigned short* G0, unsigned short* G1, unsigned short* G2)
{
    int z = blockIdx.z;
    unsigned short* p; int C;
    switch (z) {
        case 0: p = X0; C = 64; break;
        case 1: p = X1; C = 64; break;
        case 2: p = X2; C = 64; break;
        case 3: p = F0; C = 128; break;
        case 4: p = F1; C = 128; break;
        case 5: p = F2; C = 128; break;
        case 6: p = G0; C = 128; break;
        case 7: p = G1; C = 128; break;
        default: p = G2; C = 128; break;
    }
    int chunks = C >> 3;
    int total = 2 * 516 * chunks;
    int idx = blockIdx.x * 256 + threadIdx.x;
    if (idx >= total) return;
    int cb = idx % chunks;
    int pidx = idx / chunks;
    int n = pidx / 516;
    int b = pidx % 516;
    int y, x;
    if (b < 130)      { y = 0;       x = b; }
    else if (b < 260) { y = 129;     x = b - 130; }
    else if (b < 388) { y = b - 259; x = 0; }
    else              { y = b - 387; x = 129; }
    u32x4 zz = {0u, 0u, 0u, 0u};
    *(u32x4*)(p + ((size_t)((n * 130 + y) * 130 + x)) * C + cb * 8) = zz;
}

// zero borders of one C=128 padded buffer (A1p slot, launched AFTER attn)
__global__ __launch_bounds__(256) void zero_one_kernel(unsigned short* p)
{
    int idx = blockIdx.x * 256 + threadIdx.x;
    if (idx >= 2 * 516 * 16) return;
    int cb = idx & 15;
    int pidx = idx >> 4;
    int n = pidx / 516;
    int b = pidx % 516;
    int y, x;
    if (b < 130)      { y = 0;       x = b; }
    else if (b < 260) { y = 129;     x = b - 130; }
    else if (b < 388) { y = b - 259; x = 0; }
    else              { y = b - 387; x = 129; }
    u32x4 zz = {0u, 0u, 0u, 0u};
    *(u32x4*)(p + ((size_t)((n * 130 + y) * 130 + x)) * 128 + cb * 8) = zz;
}

// ---------------------------------------------------------------------------
// pack weights into MFMA A-fragment order: [tap][kc][m][lane][8 bf16]
// ---------------------------------------------------------------------------
__global__ __launch_bounds__(256) void pack_kernel(
    const float* Wc0, const float* Wadj, const float* Wc1,
    const float* Wq, const float* Wkv, const float* Wpool,
    const float* bc0, const float* badj,
    const float* g1, const float* be1, const float* m1, const float* v1,
    unsigned short* W0p, unsigned short* W1p, unsigned short* Wqp,
    unsigned short* Wkvp, unsigned short* Wpp,
    float* b0sum, float* s1a, float* t1a)
{
    int z = blockIdx.z;
    int idx = blockIdx.x * 256 + threadIdx.x;
    if (z == 5) {
        if (idx < 128) {
            int co = idx;
            b0sum[co] = bc0[co] + badj[co];
            float s = g1[co] * rsqrtf(v1[co] + 1e-5f);
            s1a[co] = s;
            t1a[co] = be1[co] - m1[co] * s;
        }
        return;
    }
    int CIN, NTAP; unsigned short* dst;
    switch (z) {
        case 0: CIN = 64;  NTAP = 10; dst = W0p;  break;
        case 1: CIN = 128; NTAP = 10; dst = W1p;  break;
        case 2: CIN = 128; NTAP = 1;  dst = Wqp;  break;
        case 3: CIN = 128; NTAP = 1;  dst = Wkvp; break;
        default: CIN = 128; NTAP = 9; dst = Wpp;  break;
    }
    int KCN = CIN / 32;
    int count = NTAP * KCN * 512;
    if (idx >= count) return;
    int lane = idx & 63;
    int m = (idx >> 6) & 7;
    int rest = idx >> 9;
    int kc = rest % KCN;
    int tap = rest / KCN;
    int co = m * 16 + (lane & 15);
    int cib = kc * 32 + ((lane >> 4) << 3);
    unsigned short vals[8];
#pragma unroll
    for (int j = 0; j < 8; ++j) {
        int ci = cib + j;
        float v;
        if (z == 0)       v = (tap < 9) ? Wc0[((size_t)co * 64 + ci) * 9 + tap] : Wadj[co * 64 + ci];
        else if (z == 1)  v = (tap < 9) ? Wc1[((size_t)co * 128 + ci) * 9 + tap] : (co == ci ? 1.0f : 0.0f);
        else if (z == 2)  v = Wq[co * 128 + ci];
        else if (z == 3)  v = Wkv[co * 128 + ci];
        else              v = Wpool[((size_t)co * 128 + ci) * 9 + tap];
        vals[j] = f2b(v);
    }
    u32x4 pk;
    pk.x = vals[0] | ((unsigned)vals[1] << 16);
    pk.y = vals[2] | ((unsigned)vals[3] << 16);
    pk.z = vals[4] | ((unsigned)vals[5] << 16);
    pk.w = vals[6] | ((unsigned)vals[7] << 16);
    *(u32x4*)(dst + (size_t)idx * 8) = pk;
}

// ---------------------------------------------------------------------------
// prep: BN0 + pad + NCHW f32 -> NHWC bf16 padded (2,130,130,64), interior only
// ---------------------------------------------------------------------------
__global__ __launch_bounds__(256) void prep_kernel(
    const float* x0, const float* x1, const float* x2,
    const float* g0, const float* be0, const float* me0, const float* va0,
    unsigned short* X0, unsigned short* X1, unsigned short* X2)
{
    const int y = blockIdx.x;
    const int mz = blockIdx.y;
    const int map = mz >> 1, n = mz & 1;
    const float* in = (map == 0 ? x0 : map == 1 ? x1 : x2) + (size_t)n * 64 * HW + y * 128;
    unsigned short* out = (map == 0 ? X0 : map == 1 ? X1 : X2)
                          + ((size_t)(n * 130 + y + 1) * 130 + 1) * 64;
    const int x = threadIdx.x & 127;
    for (int cb = threadIdx.x >> 7; cb < 8; cb += 2) {
        unsigned short vals[8];
#pragma unroll
        for (int j = 0; j < 8; ++j) {
            int ci = cb * 8 + j;
            float s = g0[ci] * rsqrtf(va0[ci] + 1e-5f);
            float t = be0[ci] - me0[ci] * s;
            vals[j] = f2b(in[(size_t)ci * HW + x] * s + t);
        }
        u32x4 pk;
        pk.x = vals[0] | ((unsigned)vals[1] << 16);
        pk.y = vals[2] | ((unsigned)vals[3] << 16);
        pk.z = vals[4] | ((unsigned)vals[5] << 16);
        pk.w = vals[6] | ((unsigned)vals[7] << 16);
        *(u32x4*)(out + (size_t)x * 64 + cb * 8) = pk;
    }
}

// ---------------------------------------------------------------------------
// conv3 v7: counted-vmcnt double-buffered pipeline, full occupancy.
// Tile: 1 out row x 64 px x 64 co (ch-half) per block, 256 thr (4 waves:
// pxh = wv&1, coq = wv>>1 -> 32px x 32co each, acc[2][2]).
// Stage: 3 rows x 68 px x 32ci per kc = 13,056 B; 2 bufs = 26,112 B ->
// 6 blocks/CU. Pipeline per kc: STAGE(next) -> s_waitcnt vmcnt(3) (prev
// stage done; 3 = min loads/thread/stage) -> raw s_barrier -> MFMA ->
// s_barrier. Loads for kc+1 stay in flight across compute(kc).
// grid 1-D 3072, XCD-bijective: wid = (bid&7)*384 + bid>>3;
//   ch = wid&1, xh = (wid>>1)&1, y = (wid>>2)&127, mz = wid>>9.
// (Staging reads <=2px past row/buffer end: lands in adjacent ws, unused.)
// ---------------------------------------------------------------------------
template <int CIN, int EPI>
__global__ __launch_bounds__(256, 6) void conv3_kernel(
    const unsigned short* I0, const unsigned short* I1, const unsigned short* I2,
    const unsigned short* Wp, const float* bA, const float* bB, const float* bC,
    unsigned short* O0, unsigned short* O1, unsigned short* O2)
{
    constexpr int KCN = CIN / 32;
    constexpr int TKY[10] = {0,0,0,1,1,1,2,2,2,1};
    constexpr int TKX[10] = {0,1,2,0,1,2,0,1,2,1};
    const int tid = threadIdx.x;
    const int lane = tid & 63;
    const int l15 = lane & 15, l4 = lane >> 4;
    const int wv = tid >> 6;
    const int pxh = wv & 1;
    const int coq = wv >> 1;
    const int bid = blockIdx.x;
    const int wid = (bid & 7) * 384 + (bid >> 3);
    const int ch = wid & 1;
    const int xh = (wid >> 1) & 1;
    const int y  = (wid >> 2) & 127;
    const int mz = wid >> 9;
    const int map = mz >> 1, n = mz & 1;
    const int gx0 = xh * 64;
    const unsigned short* In = (map == 0 ? I0 : map == 1 ? I1 : I2) + (size_t)n * 130 * 130 * CIN;
    unsigned short* On = (map == 0 ? O0 : map == 1 ? O1 : O2) + (size_t)n * 130 * 130 * 128;

    // 2 bufs x [3 rows][68 px][4 ci-chunk slots][16B] = 26,112 B
    __shared__ __align__(16) unsigned short stage[2 * 6528];

    f32x4 acc[2][2];
#pragma unroll
    for (int a = 0; a < 2; ++a)
#pragma unroll
        for (int b = 0; b < 2; ++b) acc[a][b] = (f32x4){0.f, 0.f, 0.f, 0.f};

    const int px0 = pxh * 32;
    const u32x4* Ap = (const u32x4*)Wp;

    // stage one kc-slice (816 gload16 units) into buf
    auto STAGE = [&](int buf, int kcc) {
#pragma unroll
        for (int it = 0; it < 4; ++it) {
            int idx = it * 256 + tid;
            if (idx < 816) {
                int r = idx / 272;
                int rem = idx - r * 272;
                int xx = rem >> 2;
                int slot = rem & 3;
                int cd = slot ^ ((xx >> 1) & 3);
                gload16(In + ((size_t)(y + r) * 130 + gx0 + xx) * CIN + kcc * 32 + cd * 8,
                        stage + (size_t)buf * 6528 + (size_t)(idx & ~63) * 8);
            }
        }
    };

    STAGE(0, 0);

#pragma unroll
    for (int kc = 0; kc < KCN; ++kc) {
        if (kc + 1 < KCN) {
            STAGE((kc + 1) & 1, kc + 1);
            asm volatile("s_waitcnt vmcnt(3)" ::: "memory");
        } else {
            asm volatile("s_waitcnt vmcnt(0)" ::: "memory");
        }
        __builtin_amdgcn_s_barrier();       // all waves' prev-stage loads done
        __builtin_amdgcn_sched_barrier(0);  // fence: no ds_read hoisted above
        const unsigned short* sb = stage + (size_t)(kc & 1) * 6528;
#pragma unroll
        for (int t = 0; t < 10; ++t) {
            const int ky = TKY[t], kx = TKX[t];
            u32x4 a[2];
#pragma unroll
            for (int mi = 0; mi < 2; ++mi)
                a[mi] = Ap[((size_t)(t * KCN + kc) * 8 + ch * 4 + coq * 2 + mi) * 64 + lane];
            bf16x8 bv[2];
#pragma unroll
            for (int nf = 0; nf < 2; ++nf) {
                int xx = px0 + nf * 16 + l15 + kx;
                int slot = l4 ^ ((xx >> 1) & 3);
                bv[nf] = *(const bf16x8*)(sb + ((size_t)(ky * 68 + xx) * 4 + slot) * 8);
            }
#pragma unroll
            for (int mi = 0; mi < 2; ++mi) {
                bf16x8 av = __builtin_bit_cast(bf16x8, a[mi]);
#pragma unroll
                for (int nf = 0; nf < 2; ++nf)
                    acc[mi][nf] = __builtin_amdgcn_mfma_f32_16x16x32_bf16(av, bv[nf], acc[mi][nf], 0, 0, 0);
            }
        }
        if (kc + 1 < KCN) __builtin_amdgcn_s_barrier();  // reads done before overwrite
    }

    // epilogue: bias + lrelu (+ BN1 fold for EPI 0), store NHWC bf16 interior
#pragma unroll
    for (int mi = 0; mi < 2; ++mi) {
#pragma unroll
        for (int nf = 0; nf < 2; ++nf) {
            int px = gx0 + px0 + nf * 16 + l15;
            int cobase = (ch * 4 + coq * 2 + mi) * 16 + l4 * 4;
            float t4[4];
#pragma unroll
            for (int r = 0; r < 4; ++r) {
                int co = cobase + r;
                float v = acc[mi][nf][r] + bA[co];
                v = v > 0.f ? v : 0.05f * v;
                if (EPI == 0) v = v * bB[co] + bC[co];
                t4[r] = v;
            }
            unsigned short* op = On + ((size_t)(y + 1) * 130 + (px + 1)) * 128 + cobase;
            *(unsigned*)(op)     = (unsigned)f2b(t4[0]) | ((unsigned)f2b(t4[1]) << 16);
            *(unsigned*)(op + 2) = (unsigned)f2b(t4[2]) | ((unsigned)f2b(t4[3]) << 16);
        }
    }
}

// ---------------------------------------------------------------------------
// proj: 1x1 conv GEMM. z: 0 = G0->KV0 (rows 0..129), 1 = G2->KV2, 2 = G1->Qb
// ---------------------------------------------------------------------------
__global__ __launch_bounds__(256, 4) void proj_kernel(
    const unsigned short* G0, const unsigned short* G1, const unsigned short* G2,
    const unsigned short* Wqp, const unsigned short* Wkvp,
    const float* bq, const float* bkv,
    unsigned short* KV0, unsigned short* KV2, unsigned short* Qb)
{
    const int z = blockIdx.z;
    const int proj = z >> 1, n = z & 1;
    const int yy = blockIdx.y;
    if (proj == 2 && (yy == 0 || yy == 129)) return;
    const int tid = threadIdx.x;
    const int lane = tid & 63, l15 = lane & 15, l4 = lane >> 4, wv = tid >> 6;
    const int ch = blockIdx.x;
    const unsigned short* In = (proj == 0 ? G0 : proj == 1 ? G2 : G1) + (size_t)n * 130 * 130 * 128;
    const unsigned short* Wp = (proj == 2) ? Wqp : Wkvp;
    const float* bias = (proj == 2) ? bq : bkv;

    __shared__ __align__(16) unsigned short stage[130 * 4 * 8];

    f32x4 acc[4][2];
#pragma unroll
    for (int a = 0; a < 4; ++a)
#pragma unroll
        for (int b = 0; b < 2; ++b) acc[a][b] = (f32x4){0.f, 0.f, 0.f, 0.f};

    const int px0 = wv * 32;
    const u32x4* Ap = (const u32x4*)Wp;

    for (int kc = 0; kc < 4; ++kc) {
        if (kc) __syncthreads();
        for (int idx = tid; idx < 520; idx += 256) {
            int xx = idx >> 2, slot = idx & 3;
            int cd = slot ^ ((xx >> 1) & 3);
            gload16(In + ((size_t)yy * 130 + xx) * 128 + kc * 32 + cd * 8,
                    stage + (size_t)(idx & ~63) * 8);
        }
        __syncthreads();
        u32x4 a[4];
#pragma unroll
        for (int mi = 0; mi < 4; ++mi)
            a[mi] = Ap[((size_t)kc * 8 + ch * 4 + mi) * 64 + lane];
        bf16x8 bv[2];
#pragma unroll
        for (int nf = 0; nf < 2; ++nf) {
            int xx = px0 + nf * 16 + l15 + 1;
            int slot = l4 ^ ((xx >> 1) & 3);
            bv[nf] = *(const bf16x8*)(stage + ((size_t)xx * 4 + slot) * 8);
        }
#pragma unroll
        for (int mi = 0; mi < 4; ++mi) {
            bf16x8 av = __builtin_bit_cast(bf16x8, a[mi]);
#pragma unroll
            for (int nf = 0; nf < 2; ++nf)
                acc[mi][nf] = __builtin_amdgcn_mfma_f32_16x16x32_bf16(av, bv[nf], acc[mi][nf], 0, 0, 0);
        }
        if (kc < 3) __syncthreads();
    }
#pragma unroll
    for (int mi = 0; mi < 4; ++mi) {
#pragma unroll
        for (int nf = 0; nf < 2; ++nf) {
            int px = px0 + nf * 16 + l15;
            int cobase = (ch * 4 + mi) * 16 + l4 * 4;
            float t4[4];
#pragma unroll
            for (int r = 0; r < 4; ++r) t4[r] = acc[mi][nf][r] + bias[cobase + r];
            unsigned short* op;
            if (proj == 2)
                op = Qb + ((size_t)(n * 128 + yy - 1) * 128 + px) * 128 + cobase;
            else
                op = (proj == 0 ? KV0 : KV2) + ((size_t)(n * 130 + yy) * 130 + (px + 1)) * 128 + cobase;
            *(unsigned*)(op)     = (unsigned)f2b(t4[0]) | ((unsigned)f2b(t4[1]) << 16);
            *(unsigned*)(op + 2) = (unsigned)f2b(t4[2]) | ((unsigned)f2b(t4[3]) << 16);
        }
    }
}

// KV border columns (x = 0 / 129) = bias
__global__ __launch_bounds__(256) void kv_border_kernel(
    unsigned short* KV0, unsigned short* KV2, const float* bkv)
{
    int idx = blockIdx.x * 256 + threadIdx.x;
    if (idx >= 16640) return;
    int cb = idx & 15;
    int t = idx >> 4;
    int col = t & 1; t >>= 1;
    int yy = t % 130; t /= 130;
    int n = t & 1;
    int buf = t >> 1;
    unsigned short* p = (buf ? KV2 : KV0)
        + ((size_t)(n * 130 + yy) * 130 + (col ? 129 : 0)) * 128 + cb * 8;
    u16x8 v;
#pragma unroll
    for (int j = 0; j < 8; ++j) v[j] = f2b(bkv[cb * 8 + j]);
    *(u16x8*)p = v;
}

// ---------------------------------------------------------------------------
// attention v8: BRANCH-SPLIT, fine tiles. Block = 128 thr (2y x 16px x 4h);
// KV window 4 x 20 px = 20,480 B LDS. grid 2048, XCD-bijective.
// ---------------------------------------------------------------------------
__global__ __launch_bounds__(128) void attn_kernel(
    const unsigned short* Qb, const unsigned short* KV0,
    const unsigned short* KV2, unsigned short* P0, unsigned short* P1)
{
    const int bid = blockIdx.x;
    const int wid = (bid & 7) * 256 + (bid >> 3);
    const int br  = wid & 1;
    const int r2  = wid >> 1;        // 0..1023
    const int n   = r2 >> 9;
    const int rem = r2 & 511;
    const int yt  = rem >> 3;        // 0..63
    const int xt  = rem & 7;         // 0..7
    const int y0  = yt * 2;
    const int x0  = xt * 16;

    const int tid = threadIdx.x;
    const int h   = tid & 3;
    const int pxl = (tid >> 2) & 15;
    const int py  = tid >> 6;
    const int x   = x0 + pxl;
    const int y   = y0 + py;
    const float SC = 0.17677669529663687f;   // 32^-0.5

    const unsigned short* KV = br ? KV2 : KV0;
    unsigned short* Pb = br ? P1 : P0;

    __shared__ __align__(16) unsigned short kvb[4 * 20 * 128];   // 20,480 B

#pragma unroll
    for (int it = 0; it < 10; ++it) {
        int idx = it * 128 + tid;
        int g = idx >> 6, l = idx & 63;
        int r = g / 5, s = g - r * 5;
        int px = s * 4 + (l >> 4);
        int c  = (l & 15) ^ (px & 7);
        gload16(KV + (((size_t)(n * 130 + y0 + r) * 130) + x0 + px) * 128 + c * 8,
                kvb + (size_t)g * 512);
    }

    float qf[32];
    {
        const u16x8* qp = (const u16x8*)(Qb + (((size_t)(n * 128 + y) * 128 + x) * 128) + h * 32);
#pragma unroll
        for (int d8 = 0; d8 < 4; ++d8) {
            u16x8 q8 = qp[d8];
#pragma unroll
            for (int j = 0; j < 8; ++j) qf[d8 * 8 + j] = b2f(q8[j]) * SC;
        }
    }
    __syncthreads();

    float lg[9];
#pragma unroll
    for (int t = 0; t < 9; ++t) {
        int ky = t / 3, kx = t % 3;
        int pxw = pxl + kx;
        const unsigned short* base = kvb + ((size_t)(py + ky) * 20 + pxw) * 128;
        float s = 0.f;
#pragma unroll
        for (int d8 = 0; d8 < 4; ++d8) {
            int c = ((h << 2) | d8) ^ (pxw & 7);
            u16x8 kk = *(const u16x8*)(base + c * 8);
#pragma unroll
            for (int j = 0; j < 8; ++j) s += qf[d8 * 8 + j] * b2f(kk[j]);
        }
        lg[t] = s;
    }
    float mv = lg[0];
#pragma unroll
    for (int t = 1; t < 9; ++t) mv = fmaxf(mv, lg[t]);
    float w[9], sum = 0.f;
#pragma unroll
    for (int t = 0; t < 9; ++t) { w[t] = __expf(lg[t] - mv); sum += w[t]; }
    float r = 0.5f / sum;
#pragma unroll
    for (int t = 0; t < 9; ++t) w[t] *= r;

    float o[32];
#pragma unroll
    for (int d = 0; d < 32; ++d) o[d] = 0.f;
#pragma unroll
    for (int t = 0; t < 9; ++t) {
        int ky = t / 3, kx = t % 3;
        int pxw = pxl + kx;
        const unsigned short* base = kvb + ((size_t)(py + ky) * 20 + pxw) * 128;
#pragma unroll
        for (int d8 = 0; d8 < 4; ++d8) {
            int c = ((h << 2) | d8) ^ (pxw & 7);
            u16x8 kk = *(const u16x8*)(base + c * 8);
#pragma unroll
            for (int j = 0; j < 8; ++j) o[d8 * 8 + j] += w[t] * b2f(kk[j]);
        }
    }

    unsigned short* ap = Pb + ((size_t)(n * 130 + y + 1) * 130 + (x + 1)) * 128 + h * 32;
#pragma unroll
    for (int d8 = 0; d8 < 4; ++d8) {
        u16x8 v;
#pragma unroll
        for (int j = 0; j < 8; ++j) v[j] = f2b(o[d8 * 8 + j]);
        *(u16x8*)(ap + d8 * 8) = v;
    }
}

// ---------------------------------------------------------------------------
// expand v2: A1p = P0+P1 (bf16 NHWC padded) and pass = P0+P1 (f32 NCHW).
// ---------------------------------------------------------------------------
__global__ __launch_bounds__(256) void expand_kernel(
    const unsigned short* P0, const unsigned short* P1,
    unsigned short* A1p, float* pass)
{
    const int y = blockIdx.x, n = blockIdx.y;
    const int t = threadIdx.x;
    __shared__ float lds[128][129];

    const int px = t >> 1, ch0 = (t & 1) * 64;
    size_t off = ((size_t)(n * 130 + y + 1) * 130 + px + 1) * 128 + ch0;
    const u16x8* a = (const u16x8*)(P0 + off);
    const u16x8* b = (const u16x8*)(P1 + off);
    u16x8* o = (u16x8*)(A1p + off);
    float* lrow = &lds[px][ch0];
#pragma unroll
    for (int k = 0; k < 8; ++k) {
        u16x8 va = a[k], vb = b[k];
        u16x8 vo;
#pragma unroll
        for (int j = 0; j < 8; ++j) {
            float s = b2f(va[j]) + b2f(vb[j]);
            lrow[k * 8 + j] = s;
            vo[j] = f2b(s);
        }
        o[k] = vo;
    }
    __syncthreads();

    const int c = t >> 1, xh = t & 1;
    float* dst = pass + ((size_t)(n * 128 + c) * HW) + y * 128 + xh * 64;
#pragma unroll
    for (int i = 0; i < 16; ++i) {
        f32x4 q = { lds[xh * 64 + i * 4 + 0][c], lds[xh * 64 + i * 4 + 1][c],
                    lds[xh * 64 + i * 4 + 2][c], lds[xh * 64 + i * 4 + 3][c] };
        *(f32x4*)(dst + i * 4) = q;
    }
}

// ---------------------------------------------------------------------------
// pool v3 (mi=2 x nf=2 wave tile, XCD swizzle): 3x3 stride-2 conv.
// grid 1-D 768: wid = (bid&7)*96 + bid>>3.
// ---------------------------------------------------------------------------
__global__ __launch_bounds__(256, 4) void pool_kernel(
    const unsigned short* G0, const unsigned short* A1, const unsigned short* G2,
    const unsigned short* Wpp, const float* bp, float* out)
{
    const int bid = blockIdx.x;
    const int wid = (bid & 7) * 96 + (bid >> 3);
    const int ch = wid & 1;
    const int yo = (wid >> 1) & 63;
    const int mz = wid >> 7;
    const int map = mz >> 1, n = mz & 1;
    const int tid = threadIdx.x, lane = tid & 63, l15 = lane & 15, l4 = lane >> 4, wv = tid >> 6;
    const int pxh = wv & 1, coq = wv >> 1;
    const unsigned short* In = (map == 0 ? G0 : map == 1 ? A1 : G2) + (size_t)n * 130 * 130 * 128;
    float* outp = out + (size_t)map * 1048576 + (size_t)n * 524288;

    __shared__ __align__(16) unsigned short stage[3 * 130 * 4 * 8];

    f32x4 acc[2][2];
#pragma unroll
    for (int a = 0; a < 2; ++a)
#pragma unroll
        for (int b = 0; b < 2; ++b) acc[a][b] = (f32x4){0.f, 0.f, 0.f, 0.f};

    const int px0 = pxh * 32;
    const u32x4* Ap = (const u32x4*)Wpp;

    for (int kc = 0; kc < 4; ++kc) {
        if (kc) __syncthreads();
        for (int idx = tid; idx < 1560; idx += 256) {
            int r = idx / 520;
            int rem = idx - r * 520;
            int xx = rem >> 2;
            int slot = rem & 3;
            int cd = slot ^ ((xx >> 1) & 3);
            gload16(In + ((size_t)(2 * yo + r) * 130 + xx) * 128 + kc * 32 + cd * 8,
                    stage + (size_t)(idx & ~63) * 8);
        }
        __syncthreads();
#pragma unroll
        for (int t = 0; t < 9; ++t) {
            const int ky = t / 3, kx = t % 3;
            u32x4 a[2];
#pragma unroll
            for (int mi = 0; mi < 2; ++mi)
                a[mi] = Ap[((size_t)(t * 4 + kc) * 8 + ch * 4 + coq * 2 + mi) * 64 + lane];
            bf16x8 bv[2];
#pragma unroll
            for (int nf = 0; nf < 2; ++nf) {
                int xx = 2 * (px0 + nf * 16 + l15) + kx;
                int slot = l4 ^ ((xx >> 1) & 3);
                bv[nf] = *(const bf16x8*)(stage + ((size_t)(ky * 130 + xx) * 4 + slot) * 8);
            }
#pragma unroll
            for (int mi = 0; mi < 2; ++mi) {
                bf16x8 av = __builtin_bit_cast(bf16x8, a[mi]);
#pragma unroll
                for (int nf = 0; nf < 2; ++nf)
                    acc[mi][nf] = __builtin_amdgcn_mfma_f32_16x16x32_bf16(av, bv[nf], acc[mi][nf], 0, 0, 0);
            }
        }
    }
#pragma unroll
    for (int mi = 0; mi < 2; ++mi) {
#pragma unroll
        for (int nf = 0; nf < 2; ++nf) {
            int cobase = (ch * 4 + coq * 2 + mi) * 16 + l4 * 4;
            int px = px0 + nf * 16 + l15;
#pragma unroll
            for (int r = 0; r < 4; ++r) {
                int co = cobase + r;
                outp[((size_t)co * 64 + yo) * 64 + px] = acc[mi][nf][r] + bp[co];
            }
        }
    }
}

// ---------------------------------------------------------------------------
extern "C" void kernel_launch(void* const* d_in, const int* in_sizes, int n_in,
                              void* d_out, int out_size, void* d_ws, size_t ws_size,
                              hipStream_t stream)
{
    const float* x0 = (const float*)d_in[0];
    const float* x1 = (const float*)d_in[1];
    const float* x2 = (const float*)d_in[2];
    const float* gamma0 = (const float*)d_in[3];
    const float* beta0  = (const float*)d_in[4];
    const float* mean0  = (const float*)d_in[5];
    const float* var0   = (const float*)d_in[6];
    const float* gamma1 = (const float*)d_in[7];
    const float* beta1  = (const float*)d_in[8];
    const float* mean1  = (const float*)d_in[9];
    const float* var1   = (const float*)d_in[10];
    const float* W_adj  = (const float*)d_in[11];
    const float* b_adj  = (const float*)d_in[12];
    const float* W_conv0 = (const float*)d_in[13];
    const float* b_conv0 = (const float*)d_in[14];
    const float* W_conv1 = (const float*)d_in[15];
    const float* b_conv1 = (const float*)d_in[16];
    const float* Wq  = (const float*)d_in[17];
    const float* bq  = (const float*)d_in[18];
    const float* Wkv = (const float*)d_in[19];
    const float* bkv = (const float*)d_in[20];
    const float* W_pool = (const float*)d_in[21];
    const float* b_pool = (const float*)d_in[22];

    float* out  = (float*)d_out;
    float* pass = out + 3145728;                 // (2,128,128,128) f32 NCHW

    char* wsb = (char*)d_ws;
    const size_t FSZ = 8652800;                  // 2*130*130*128*2 B
    const size_t XSZ = 4326400;                  // 2*130*130*64*2 B
    unsigned short* F0 = (unsigned short*)(wsb);
    unsigned short* F1 = (unsigned short*)(wsb + FSZ);
    unsigned short* F2 = (unsigned short*)(wsb + 2 * FSZ);
    unsigned short* G0 = (unsigned short*)(wsb + 3 * FSZ);
    unsigned short* G1 = (unsigned short*)(wsb + 4 * FSZ);
    unsigned short* G2 = (unsigned short*)(wsb + 5 * FSZ);
    unsigned short* X0 = (unsigned short*)(wsb + 6 * FSZ);
    unsigned short* X1 = (unsigned short*)(wsb + 6 * FSZ + XSZ);
    unsigned short* X2 = (unsigned short*)(wsb + 6 * FSZ + 2 * XSZ);
    char* WAR = wsb + 6 * FSZ + 3 * XSZ;
    unsigned short* W0p    = (unsigned short*)(WAR);
    unsigned short* W1p    = (unsigned short*)(WAR + 163840);
    unsigned short* Wqp    = (unsigned short*)(WAR + 491520);
    unsigned short* Wkvp   = (unsigned short*)(WAR + 524288);
    unsigned short* Wpoolp = (unsigned short*)(WAR + 557056);
    float* b0sum = (float*)(WAR + 851968);
    float* s1a   = (float*)(WAR + 852480);
    float* t1a   = (float*)(WAR + 852992);
    // aliases (lifetimes disjoint, stream-ordered):
    unsigned short* KV0 = F0;    // live: proj -> attn
    unsigned short* KV2 = F1;    // live: proj -> attn
    unsigned short* Qb  = F2;    // live: proj -> attn
    unsigned short* P0  = G1;    // G1 dead after proj; live: attn -> expand
    unsigned short* P1  = X0;    // spans X0+X1 (dead after conv3<64>)
    unsigned short* A1p = F0;    // KV0 slot, dead after attn; live: expand -> pool

    zero_borders_kernel<<<dim3(65, 1, 9), 256, 0, stream>>>(X0, X1, X2, F0, F1, F2, G0, G1, G2);
    pack_kernel<<<dim3(80, 1, 6), 256, 0, stream>>>(
        W_conv0, W_adj, W_conv1, Wq, Wkv, W_pool, b_conv0, b_adj,
        gamma1, beta1, mean1, var1, W0p, W1p, Wqp, Wkvp, Wpoolp, b0sum, s1a, t1a);
    prep_kernel<<<dim3(128, 6), 256, 0, stream>>>(
        x0, x1, x2, gamma0, beta0, mean0, var0, X0, X1, X2);

    conv3_kernel<64, 0><<<dim3(3072), 256, 0, stream>>>(
        X0, X1, X2, W0p, b0sum, s1a, t1a, F0, F1, F2);
    conv3_kernel<128, 1><<<dim3(3072), 256, 0, stream>>>(
        F0, F1, F2, W1p, b_conv1, nullptr, nullptr, G0, G1, G2);

    proj_kernel<<<dim3(2, 130, 6), 256, 0, stream>>>(
        G0, G1, G2, Wqp, Wkvp, bq, bkv, KV0, KV2, Qb);
    kv_border_kernel<<<dim3(65), 256, 0, stream>>>(KV0, KV2, bkv);

    attn_kernel<<<dim3(2048), 128, 0, stream>>>(Qb, KV0, KV2, P0, P1);

    zero_one_kernel<<<dim3(65), 256, 0, stream>>>(A1p);
    expand_kernel<<<dim3(128, 2), 256, 0, stream>>>(P0, P1, A1p, pass);

    pool_kernel<<<dim3(768), 256, 0, stream>>>(G0, A1p, G2, Wpoolp, b_pool, out);
}

// Round 16
// 171.931 us; speedup vs baseline: 1.0545x; 1.0545x over previous
//
#include <hip/hip_runtime.h>
#include <cstdint>
#include <cstddef>

// ---------------------------------------------------------------------------
// Types / helpers
// ---------------------------------------------------------------------------
typedef __bf16 bf16x8 __attribute__((ext_vector_type(8)));
typedef float f32x4 __attribute__((ext_vector_type(4)));
typedef unsigned short u16x8 __attribute__((ext_vector_type(8)));
typedef unsigned int u32x4 __attribute__((ext_vector_type(4)));

#define AS1 __attribute__((address_space(1)))
#define AS3 __attribute__((address_space(3)))

__device__ __forceinline__ void gload16(const void* g, void* l) {
    // async global->LDS, 16B per lane; LDS dest = wave-uniform base + lane*16
    __builtin_amdgcn_global_load_lds((AS1 unsigned int*)(unsigned long long)g,
                                     (AS3 unsigned int*)l, 16, 0, 0);
}

__device__ __forceinline__ unsigned short f2b(float f) {  // f32 -> bf16 RNE
    unsigned u = __builtin_bit_cast(unsigned, f);
    return (unsigned short)((u + 0x7fffu + ((u >> 16) & 1u)) >> 16);
}
__device__ __forceinline__ float b2f(unsigned short h) {
    return __builtin_bit_cast(float, ((unsigned)h) << 16);
}

static constexpr int HW = 16384;

// ---------------------------------------------------------------------------
// zero borders of 9 padded NHWC buffers (X*: C=64, F*/G*: C=128)
// ---------------------------------------------------------------------------
__global__ __launch_bounds__(256) void zero_borders_kernel(
    unsigned short* X0, unsigned short* X1, unsigned short* X2,
    unsigned short* F0, unsigned short* F1, unsigned short* F2,
    unsigned short* G0, unsigned short* G1, unsigned short* G2)
{
    int z = blockIdx.z;
    unsigned short* p; int C;
    switch (z) {
        case 0: p = X0; C = 64; break;
        case 1: p = X1; C = 64; break;
        case 2: p = X2; C = 64; break;
        case 3: p = F0; C = 128; break;
        case 4: p = F1; C = 128; break;
        case 5: p = F2; C = 128; break;
        case 6: p = G0; C = 128; break;
        case 7: p = G1; C = 128; break;
        default: p = G2; C = 128; break;
    }
    int chunks = C >> 3;
    int total = 2 * 516 * chunks;
    int idx = blockIdx.x * 256 + threadIdx.x;
    if (idx >= total) return;
    int cb = idx % chunks;
    int pidx = idx / chunks;
    int n = pidx / 516;
    int b = pidx % 516;
    int y, x;
    if (b < 130)      { y = 0;       x = b; }
    else if (b < 260) { y = 129;     x = b - 130; }
    else if (b < 388) { y = b - 259; x = 0; }
    else              { y = b - 387; x = 129; }
    u32x4 zz = {0u, 0u, 0u, 0u};
    *(u32x4*)(p + ((size_t)((n * 130 + y) * 130 + x)) * C + cb * 8) = zz;
}

// zero borders of one C=128 padded buffer (A1p slot, launched AFTER attn)
__global__ __launch_bounds__(256) void zero_one_kernel(unsigned short* p)
{
    int idx = blockIdx.x * 256 + threadIdx.x;
    if (idx >= 2 * 516 * 16) return;
    int cb = idx & 15;
    int pidx = idx >> 4;
    int n = pidx / 516;
    int b = pidx % 516;
    int y, x;
    if (b < 130)      { y = 0;       x = b; }
    else if (b < 260) { y = 129;     x = b - 130; }
    else if (b < 388) { y = b - 259; x = 0; }
    else              { y = b - 387; x = 129; }
    u32x4 zz = {0u, 0u, 0u, 0u};
    *(u32x4*)(p + ((size_t)((n * 130 + y) * 130 + x)) * 128 + cb * 8) = zz;
}

// ---------------------------------------------------------------------------
// pack weights into MFMA A-fragment order: [tap][kc][m][lane][8 bf16]
// ---------------------------------------------------------------------------
__global__ __launch_bounds__(256) void pack_kernel(
    const float* Wc0, const float* Wadj, const float* Wc1,
    const float* Wq, const float* Wkv, const float* Wpool,
    const float* bc0, const float* badj,
    const float* g1, const float* be1, const float* m1, const float* v1,
    unsigned short* W0p, unsigned short* W1p, unsigned short* Wqp,
    unsigned short* Wkvp, unsigned short* Wpp,
    float* b0sum, float* s1a, float* t1a)
{
    int z = blockIdx.z;
    int idx = blockIdx.x * 256 + threadIdx.x;
    if (z == 5) {
        if (idx < 128) {
            int co = idx;
            b0sum[co] = bc0[co] + badj[co];
            float s = g1[co] * rsqrtf(v1[co] + 1e-5f);
            s1a[co] = s;
            t1a[co] = be1[co] - m1[co] * s;
        }
        return;
    }
    int CIN, NTAP; unsigned short* dst;
    switch (z) {
        case 0: CIN = 64;  NTAP = 10; dst = W0p;  break;
        case 1: CIN = 128; NTAP = 10; dst = W1p;  break;
        case 2: CIN = 128; NTAP = 1;  dst = Wqp;  break;
        case 3: CIN = 128; NTAP = 1;  dst = Wkvp; break;
        default: CIN = 128; NTAP = 9; dst = Wpp;  break;
    }
    int KCN = CIN / 32;
    int count = NTAP * KCN * 512;
    if (idx >= count) return;
    int lane = idx & 63;
    int m = (idx >> 6) & 7;
    int rest = idx >> 9;
    int kc = rest % KCN;
    int tap = rest / KCN;
    int co = m * 16 + (lane & 15);
    int cib = kc * 32 + ((lane >> 4) << 3);
    unsigned short vals[8];
#pragma unroll
    for (int j = 0; j < 8; ++j) {
        int ci = cib + j;
        float v;
        if (z == 0)       v = (tap < 9) ? Wc0[((size_t)co * 64 + ci) * 9 + tap] : Wadj[co * 64 + ci];
        else if (z == 1)  v = (tap < 9) ? Wc1[((size_t)co * 128 + ci) * 9 + tap] : (co == ci ? 1.0f : 0.0f);
        else if (z == 2)  v = Wq[co * 128 + ci];
        else if (z == 3)  v = Wkv[co * 128 + ci];
        else              v = Wpool[((size_t)co * 128 + ci) * 9 + tap];
        vals[j] = f2b(v);
    }
    u32x4 pk;
    pk.x = vals[0] | ((unsigned)vals[1] << 16);
    pk.y = vals[2] | ((unsigned)vals[3] << 16);
    pk.z = vals[4] | ((unsigned)vals[5] << 16);
    pk.w = vals[6] | ((unsigned)vals[7] << 16);
    *(u32x4*)(dst + (size_t)idx * 8) = pk;
}

// ---------------------------------------------------------------------------
// prep: BN0 + pad + NCHW f32 -> NHWC bf16 padded (2,130,130,64), interior only
// ---------------------------------------------------------------------------
__global__ __launch_bounds__(256) void prep_kernel(
    const float* x0, const float* x1, const float* x2,
    const float* g0, const float* be0, const float* me0, const float* va0,
    unsigned short* X0, unsigned short* X1, unsigned short* X2)
{
    const int y = blockIdx.x;
    const int mz = blockIdx.y;
    const int map = mz >> 1, n = mz & 1;
    const float* in = (map == 0 ? x0 : map == 1 ? x1 : x2) + (size_t)n * 64 * HW + y * 128;
    unsigned short* out = (map == 0 ? X0 : map == 1 ? X1 : X2)
                          + ((size_t)(n * 130 + y + 1) * 130 + 1) * 64;
    const int x = threadIdx.x & 127;
    for (int cb = threadIdx.x >> 7; cb < 8; cb += 2) {
        unsigned short vals[8];
#pragma unroll
        for (int j = 0; j < 8; ++j) {
            int ci = cb * 8 + j;
            float s = g0[ci] * rsqrtf(va0[ci] + 1e-5f);
            float t = be0[ci] - me0[ci] * s;
            vals[j] = f2b(in[(size_t)ci * HW + x] * s + t);
        }
        u32x4 pk;
        pk.x = vals[0] | ((unsigned)vals[1] << 16);
        pk.y = vals[2] | ((unsigned)vals[3] << 16);
        pk.z = vals[4] | ((unsigned)vals[5] << 16);
        pk.w = vals[6] | ((unsigned)vals[7] << 16);
        *(u32x4*)(out + (size_t)x * 64 + cb * 8) = pk;
    }
}

// ---------------------------------------------------------------------------
// conv3 v5 (R14 best): XCD-contiguous grid 1536, wave tile mi=2 x nf=4
// (64px x 32co). Simple 2-barrier kc loop, 6 blocks/CU.
// ---------------------------------------------------------------------------
template <int CIN, int EPI>
__global__ __launch_bounds__(256, 6) void conv3_kernel(
    const unsigned short* I0, const unsigned short* I1, const unsigned short* I2,
    const unsigned short* Wp, const float* bA, const float* bB, const float* bC,
    unsigned short* O0, unsigned short* O1, unsigned short* O2)
{
    constexpr int KCN = CIN / 32;
    constexpr int TKY[10] = {0,0,0,1,1,1,2,2,2,1};
    constexpr int TKX[10] = {0,1,2,0,1,2,0,1,2,1};
    const int tid = threadIdx.x;
    const int lane = tid & 63;
    const int l15 = lane & 15, l4 = lane >> 4;
    const int wv = tid >> 6;
    const int pxh = wv & 1;
    const int coq = wv >> 1;
    const int bid = blockIdx.x;
    const int wid = (bid & 7) * 192 + (bid >> 3);
    const int ch = wid & 1;
    const int y  = (wid >> 1) & 127;
    const int mz = wid >> 8;
    const int map = mz >> 1, n = mz & 1;
    const unsigned short* In = (map == 0 ? I0 : map == 1 ? I1 : I2) + (size_t)n * 130 * 130 * CIN;
    unsigned short* On = (map == 0 ? O0 : map == 1 ? O1 : O2) + (size_t)n * 130 * 130 * 128;

    __shared__ __align__(16) unsigned short stage[3 * 130 * 4 * 8];  // 24,960 B

    f32x4 acc[2][4];
#pragma unroll
    for (int a = 0; a < 2; ++a)
#pragma unroll
        for (int b = 0; b < 4; ++b) acc[a][b] = (f32x4){0.f, 0.f, 0.f, 0.f};

    const int px0 = pxh * 64;
    const u32x4* Ap = (const u32x4*)Wp;

    for (int kc = 0; kc < KCN; ++kc) {
        if (kc) __syncthreads();
        for (int idx = tid; idx < 1560; idx += 256) {
            int r = idx / 520;
            int rem = idx - r * 520;
            int xx = rem >> 2;
            int slot = rem & 3;
            int cd = slot ^ ((xx >> 1) & 3);
            const unsigned short* src = In + ((size_t)(y + r) * 130 + xx) * CIN + kc * 32 + cd * 8;
            gload16(src, stage + (size_t)(idx & ~63) * 8);
        }
        __syncthreads();
#pragma unroll
        for (int t = 0; t < 10; ++t) {
            const int ky = TKY[t], kx = TKX[t];
            u32x4 a[2];
#pragma unroll
            for (int mi = 0; mi < 2; ++mi)
                a[mi] = Ap[((size_t)(t * KCN + kc) * 8 + ch * 4 + coq * 2 + mi) * 64 + lane];
            bf16x8 bv[4];
#pragma unroll
            for (int nf = 0; nf < 4; ++nf) {
                int xx = px0 + nf * 16 + l15 + kx;
                int slot = l4 ^ ((xx >> 1) & 3);
                bv[nf] = *(const bf16x8*)(stage + ((size_t)(ky * 130 + xx) * 4 + slot) * 8);
            }
#pragma unroll
            for (int mi = 0; mi < 2; ++mi) {
                bf16x8 av = __builtin_bit_cast(bf16x8, a[mi]);
#pragma unroll
                for (int nf = 0; nf < 4; ++nf)
                    acc[mi][nf] = __builtin_amdgcn_mfma_f32_16x16x32_bf16(av, bv[nf], acc[mi][nf], 0, 0, 0);
            }
        }
    }
#pragma unroll
    for (int mi = 0; mi < 2; ++mi) {
#pragma unroll
        for (int nf = 0; nf < 4; ++nf) {
            int px = px0 + nf * 16 + l15;
            int cobase = (ch * 4 + coq * 2 + mi) * 16 + l4 * 4;
            float t4[4];
#pragma unroll
            for (int r = 0; r < 4; ++r) {
                int co = cobase + r;
                float v = acc[mi][nf][r] + bA[co];
                v = v > 0.f ? v : 0.05f * v;
                if (EPI == 0) v = v * bB[co] + bC[co];
                t4[r] = v;
            }
            unsigned short* op = On + ((size_t)(y + 1) * 130 + (px + 1)) * 128 + cobase;
            *(unsigned*)(op)     = (unsigned)f2b(t4[0]) | ((unsigned)f2b(t4[1]) << 16);
            *(unsigned*)(op + 2) = (unsigned)f2b(t4[2]) | ((unsigned)f2b(t4[3]) << 16);
        }
    }
}

// ---------------------------------------------------------------------------
// proj: 1x1 conv GEMM. z: 0 = G0->KV0 (rows 0..129), 1 = G2->KV2, 2 = G1->Qb
// ---------------------------------------------------------------------------
__global__ __launch_bounds__(256, 4) void proj_kernel(
    const unsigned short* G0, const unsigned short* G1, const unsigned short* G2,
    const unsigned short* Wqp, const unsigned short* Wkvp,
    const float* bq, const float* bkv,
    unsigned short* KV0, unsigned short* KV2, unsigned short* Qb)
{
    const int z = blockIdx.z;
    const int proj = z >> 1, n = z & 1;
    const int yy = blockIdx.y;
    if (proj == 2 && (yy == 0 || yy == 129)) return;
    const int tid = threadIdx.x;
    const int lane = tid & 63, l15 = lane & 15, l4 = lane >> 4, wv = tid >> 6;
    const int ch = blockIdx.x;
    const unsigned short* In = (proj == 0 ? G0 : proj == 1 ? G2 : G1) + (size_t)n * 130 * 130 * 128;
    const unsigned short* Wp = (proj == 2) ? Wqp : Wkvp;
    const float* bias = (proj == 2) ? bq : bkv;

    __shared__ __align__(16) unsigned short stage[130 * 4 * 8];

    f32x4 acc[4][2];
#pragma unroll
    for (int a = 0; a < 4; ++a)
#pragma unroll
        for (int b = 0; b < 2; ++b) acc[a][b] = (f32x4){0.f, 0.f, 0.f, 0.f};

    const int px0 = wv * 32;
    const u32x4* Ap = (const u32x4*)Wp;

    for (int kc = 0; kc < 4; ++kc) {
        if (kc) __syncthreads();
        for (int idx = tid; idx < 520; idx += 256) {
            int xx = idx >> 2, slot = idx & 3;
            int cd = slot ^ ((xx >> 1) & 3);
            gload16(In + ((size_t)yy * 130 + xx) * 128 + kc * 32 + cd * 8,
                    stage + (size_t)(idx & ~63) * 8);
        }
        __syncthreads();
        u32x4 a[4];
#pragma unroll
        for (int mi = 0; mi < 4; ++mi)
            a[mi] = Ap[((size_t)kc * 8 + ch * 4 + mi) * 64 + lane];
        bf16x8 bv[2];
#pragma unroll
        for (int nf = 0; nf < 2; ++nf) {
            int xx = px0 + nf * 16 + l15 + 1;
            int slot = l4 ^ ((xx >> 1) & 3);
            bv[nf] = *(const bf16x8*)(stage + ((size_t)xx * 4 + slot) * 8);
        }
#pragma unroll
        for (int mi = 0; mi < 4; ++mi) {
            bf16x8 av = __builtin_bit_cast(bf16x8, a[mi]);
#pragma unroll
            for (int nf = 0; nf < 2; ++nf)
                acc[mi][nf] = __builtin_amdgcn_mfma_f32_16x16x32_bf16(av, bv[nf], acc[mi][nf], 0, 0, 0);
        }
        if (kc < 3) __syncthreads();
    }
#pragma unroll
    for (int mi = 0; mi < 4; ++mi) {
#pragma unroll
        for (int nf = 0; nf < 2; ++nf) {
            int px = px0 + nf * 16 + l15;
            int cobase = (ch * 4 + mi) * 16 + l4 * 4;
            float t4[4];
#pragma unroll
            for (int r = 0; r < 4; ++r) t4[r] = acc[mi][nf][r] + bias[cobase + r];
            unsigned short* op;
            if (proj == 2)
                op = Qb + ((size_t)(n * 128 + yy - 1) * 128 + px) * 128 + cobase;
            else
                op = (proj == 0 ? KV0 : KV2) + ((size_t)(n * 130 + yy) * 130 + (px + 1)) * 128 + cobase;
            *(unsigned*)(op)     = (unsigned)f2b(t4[0]) | ((unsigned)f2b(t4[1]) << 16);
            *(unsigned*)(op + 2) = (unsigned)f2b(t4[2]) | ((unsigned)f2b(t4[3]) << 16);
        }
    }
}

// KV border columns (x = 0 / 129) = bias
__global__ __launch_bounds__(256) void kv_border_kernel(
    unsigned short* KV0, unsigned short* KV2, const float* bkv)
{
    int idx = blockIdx.x * 256 + threadIdx.x;
    if (idx >= 16640) return;
    int cb = idx & 15;
    int t = idx >> 4;
    int col = t & 1; t >>= 1;
    int yy = t % 130; t /= 130;
    int n = t & 1;
    int buf = t >> 1;
    unsigned short* p = (buf ? KV2 : KV0)
        + ((size_t)(n * 130 + yy) * 130 + (col ? 129 : 0)) * 128 + cb * 8;
    u16x8 v;
#pragma unroll
    for (int j = 0; j < 8; ++j) v[j] = f2b(bkv[cb * 8 + j]);
    *(u16x8*)p = v;
}

// ---------------------------------------------------------------------------
// attention v8 (R14 best): BRANCH-SPLIT, fine tiles. Block = 128 thr
// (2y x 16px x 4h); KV window 4 x 20 px = 20,480 B LDS. grid 2048,
// XCD-bijective. Q direct->reg.
// ---------------------------------------------------------------------------
__global__ __launch_bounds__(128) void attn_kernel(
    const unsigned short* Qb, const unsigned short* KV0,
    const unsigned short* KV2, unsigned short* P0, unsigned short* P1)
{
    const int bid = blockIdx.x;
    const int wid = (bid & 7) * 256 + (bid >> 3);
    const int br  = wid & 1;
    const int r2  = wid >> 1;        // 0..1023
    const int n   = r2 >> 9;
    const int rem = r2 & 511;
    const int yt  = rem >> 3;        // 0..63
    const int xt  = rem & 7;         // 0..7
    const int y0  = yt * 2;
    const int x0  = xt * 16;

    const int tid = threadIdx.x;
    const int h   = tid & 3;
    const int pxl = (tid >> 2) & 15;
    const int py  = tid >> 6;
    const int x   = x0 + pxl;
    const int y   = y0 + py;
    const float SC = 0.17677669529663687f;   // 32^-0.5

    const unsigned short* KV = br ? KV2 : KV0;
    unsigned short* Pb = br ? P1 : P0;

    __shared__ __align__(16) unsigned short kvb[4 * 20 * 128];   // 20,480 B

#pragma unroll
    for (int it = 0; it < 10; ++it) {
        int idx = it * 128 + tid;
        int g = idx >> 6, l = idx & 63;
        int r = g / 5, s = g - r * 5;
        int px = s * 4 + (l >> 4);
        int c  = (l & 15) ^ (px & 7);
        gload16(KV + (((size_t)(n * 130 + y0 + r) * 130) + x0 + px) * 128 + c * 8,
                kvb + (size_t)g * 512);
    }

    float qf[32];
    {
        const u16x8* qp = (const u16x8*)(Qb + (((size_t)(n * 128 + y) * 128 + x) * 128) + h * 32);
#pragma unroll
        for (int d8 = 0; d8 < 4; ++d8) {
            u16x8 q8 = qp[d8];
#pragma unroll
            for (int j = 0; j < 8; ++j) qf[d8 * 8 + j] = b2f(q8[j]) * SC;
        }
    }
    __syncthreads();

    float lg[9];
#pragma unroll
    for (int t = 0; t < 9; ++t) {
        int ky = t / 3, kx = t % 3;
        int pxw = pxl + kx;
        const unsigned short* base = kvb + ((size_t)(py + ky) * 20 + pxw) * 128;
        float s = 0.f;
#pragma unroll
        for (int d8 = 0; d8 < 4; ++d8) {
            int c = ((h << 2) | d8) ^ (pxw & 7);
            u16x8 kk = *(const u16x8*)(base + c * 8);
#pragma unroll
            for (int j = 0; j < 8; ++j) s += qf[d8 * 8 + j] * b2f(kk[j]);
        }
        lg[t] = s;
    }
    float mv = lg[0];
#pragma unroll
    for (int t = 1; t < 9; ++t) mv = fmaxf(mv, lg[t]);
    float w[9], sum = 0.f;
#pragma unroll
    for (int t = 0; t < 9; ++t) { w[t] = __expf(lg[t] - mv); sum += w[t]; }
    float r = 0.5f / sum;
#pragma unroll
    for (int t = 0; t < 9; ++t) w[t] *= r;

    float o[32];
#pragma unroll
    for (int d = 0; d < 32; ++d) o[d] = 0.f;
#pragma unroll
    for (int t = 0; t < 9; ++t) {
        int ky = t / 3, kx = t % 3;
        int pxw = pxl + kx;
        const unsigned short* base = kvb + ((size_t)(py + ky) * 20 + pxw) * 128;
#pragma unroll
        for (int d8 = 0; d8 < 4; ++d8) {
            int c = ((h << 2) | d8) ^ (pxw & 7);
            u16x8 kk = *(const u16x8*)(base + c * 8);
#pragma unroll
            for (int j = 0; j < 8; ++j) o[d8 * 8 + j] += w[t] * b2f(kk[j]);
        }
    }

    unsigned short* ap = Pb + ((size_t)(n * 130 + y + 1) * 130 + (x + 1)) * 128 + h * 32;
#pragma unroll
    for (int d8 = 0; d8 < 4; ++d8) {
        u16x8 v;
#pragma unroll
        for (int j = 0; j < 8; ++j) v[j] = f2b(o[d8 * 8 + j]);
        *(u16x8*)(ap + d8 * 8) = v;
    }
}

// ---------------------------------------------------------------------------
// expand v2: A1p = P0+P1 (bf16 NHWC padded) and pass = P0+P1 (f32 NCHW).
// ---------------------------------------------------------------------------
__global__ __launch_bounds__(256) void expand_kernel(
    const unsigned short* P0, const unsigned short* P1,
    unsigned short* A1p, float* pass)
{
    const int y = blockIdx.x, n = blockIdx.y;
    const int t = threadIdx.x;
    __shared__ float lds[128][129];

    const int px = t >> 1, ch0 = (t & 1) * 64;
    size_t off = ((size_t)(n * 130 + y + 1) * 130 + px + 1) * 128 + ch0;
    const u16x8* a = (const u16x8*)(P0 + off);
    const u16x8* b = (const u16x8*)(P1 + off);
    u16x8* o = (u16x8*)(A1p + off);
    float* lrow = &lds[px][ch0];
#pragma unroll
    for (int k = 0; k < 8; ++k) {
        u16x8 va = a[k], vb = b[k];
        u16x8 vo;
#pragma unroll
        for (int j = 0; j < 8; ++j) {
            float s = b2f(va[j]) + b2f(vb[j]);
            lrow[k * 8 + j] = s;
            vo[j] = f2b(s);
        }
        o[k] = vo;
    }
    __syncthreads();

    const int c = t >> 1, xh = t & 1;
    float* dst = pass + ((size_t)(n * 128 + c) * HW) + y * 128 + xh * 64;
#pragma unroll
    for (int i = 0; i < 16; ++i) {
        f32x4 q = { lds[xh * 64 + i * 4 + 0][c], lds[xh * 64 + i * 4 + 1][c],
                    lds[xh * 64 + i * 4 + 2][c], lds[xh * 64 + i * 4 + 3][c] };
        *(f32x4*)(dst + i * 4) = q;
    }
}

// ---------------------------------------------------------------------------
// pool v3 (mi=2 x nf=2 wave tile, XCD swizzle): 3x3 stride-2 conv.
// grid 1-D 768: wid = (bid&7)*96 + bid>>3.
// ---------------------------------------------------------------------------
__global__ __launch_bounds__(256, 4) void pool_kernel(
    const unsigned short* G0, const unsigned short* A1, const unsigned short* G2,
    const unsigned short* Wpp, const float* bp, float* out)
{
    const int bid = blockIdx.x;
    const int wid = (bid & 7) * 96 + (bid >> 3);
    const int ch = wid & 1;
    const int yo = (wid >> 1) & 63;
    const int mz = wid >> 7;
    const int map = mz >> 1, n = mz & 1;
    const int tid = threadIdx.x, lane = tid & 63, l15 = lane & 15, l4 = lane >> 4, wv = tid >> 6;
    const int pxh = wv & 1, coq = wv >> 1;
    const unsigned short* In = (map == 0 ? G0 : map == 1 ? A1 : G2) + (size_t)n * 130 * 130 * 128;
    float* outp = out + (size_t)map * 1048576 + (size_t)n * 524288;

    __shared__ __align__(16) unsigned short stage[3 * 130 * 4 * 8];

    f32x4 acc[2][2];
#pragma unroll
    for (int a = 0; a < 2; ++a)
#pragma unroll
        for (int b = 0; b < 2; ++b) acc[a][b] = (f32x4){0.f, 0.f, 0.f, 0.f};

    const int px0 = pxh * 32;
    const u32x4* Ap = (const u32x4*)Wpp;

    for (int kc = 0; kc < 4; ++kc) {
        if (kc) __syncthreads();
        for (int idx = tid; idx < 1560; idx += 256) {
            int r = idx / 520;
            int rem = idx - r * 520;
            int xx = rem >> 2;
            int slot = rem & 3;
            int cd = slot ^ ((xx >> 1) & 3);
            gload16(In + ((size_t)(2 * yo + r) * 130 + xx) * 128 + kc * 32 + cd * 8,
                    stage + (size_t)(idx & ~63) * 8);
        }
        __syncthreads();
#pragma unroll
        for (int t = 0; t < 9; ++t) {
            const int ky = t / 3, kx = t % 3;
            u32x4 a[2];
#pragma unroll
            for (int mi = 0; mi < 2; ++mi)
                a[mi] = Ap[((size_t)(t * 4 + kc) * 8 + ch * 4 + coq * 2 + mi) * 64 + lane];
            bf16x8 bv[2];
#pragma unroll
            for (int nf = 0; nf < 2; ++nf) {
                int xx = 2 * (px0 + nf * 16 + l15) + kx;
                int slot = l4 ^ ((xx >> 1) & 3);
                bv[nf] = *(const bf16x8*)(stage + ((size_t)(ky * 130 + xx) * 4 + slot) * 8);
            }
#pragma unroll
            for (int mi = 0; mi < 2; ++mi) {
                bf16x8 av = __builtin_bit_cast(bf16x8, a[mi]);
#pragma unroll
                for (int nf = 0; nf < 2; ++nf)
                    acc[mi][nf] = __builtin_amdgcn_mfma_f32_16x16x32_bf16(av, bv[nf], acc[mi][nf], 0, 0, 0);
            }
        }
    }
#pragma unroll
    for (int mi = 0; mi < 2; ++mi) {
#pragma unroll
        for (int nf = 0; nf < 2; ++nf) {
            int cobase = (ch * 4 + coq * 2 + mi) * 16 + l4 * 4;
            int px = px0 + nf * 16 + l15;
#pragma unroll
            for (int r = 0; r < 4; ++r) {
                int co = cobase + r;
                outp[((size_t)co * 64 + yo) * 64 + px] = acc[mi][nf][r] + bp[co];
            }
        }
    }
}

// ---------------------------------------------------------------------------
extern "C" void kernel_launch(void* const* d_in, const int* in_sizes, int n_in,
                              void* d_out, int out_size, void* d_ws, size_t ws_size,
                              hipStream_t stream)
{
    const float* x0 = (const float*)d_in[0];
    const float* x1 = (const float*)d_in[1];
    const float* x2 = (const float*)d_in[2];
    const float* gamma0 = (const float*)d_in[3];
    const float* beta0  = (const float*)d_in[4];
    const float* mean0  = (const float*)d_in[5];
    const float* var0   = (const float*)d_in[6];
    const float* gamma1 = (const float*)d_in[7];
    const float* beta1  = (const float*)d_in[8];
    const float* mean1  = (const float*)d_in[9];
    const float* var1   = (const float*)d_in[10];
    const float* W_adj  = (const float*)d_in[11];
    const float* b_adj  = (const float*)d_in[12];
    const float* W_conv0 = (const float*)d_in[13];
    const float* b_conv0 = (const float*)d_in[14];
    const float* W_conv1 = (const float*)d_in[15];
    const float* b_conv1 = (const float*)d_in[16];
    const float* Wq  = (const float*)d_in[17];
    const float* bq  = (const float*)d_in[18];
    const float* Wkv = (const float*)d_in[19];
    const float* bkv = (const float*)d_in[20];
    const float* W_pool = (const float*)d_in[21];
    const float* b_pool = (const float*)d_in[22];

    float* out  = (float*)d_out;
    float* pass = out + 3145728;                 // (2,128,128,128) f32 NCHW

    char* wsb = (char*)d_ws;
    const size_t FSZ = 8652800;                  // 2*130*130*128*2 B
    const size_t XSZ = 4326400;                  // 2*130*130*64*2 B
    unsigned short* F0 = (unsigned short*)(wsb);
    unsigned short* F1 = (unsigned short*)(wsb + FSZ);
    unsigned short* F2 = (unsigned short*)(wsb + 2 * FSZ);
    unsigned short* G0 = (unsigned short*)(wsb + 3 * FSZ);
    unsigned short* G1 = (unsigned short*)(wsb + 4 * FSZ);
    unsigned short* G2 = (unsigned short*)(wsb + 5 * FSZ);
    unsigned short* X0 = (unsigned short*)(wsb + 6 * FSZ);
    unsigned short* X1 = (unsigned short*)(wsb + 6 * FSZ + XSZ);
    unsigned short* X2 = (unsigned short*)(wsb + 6 * FSZ + 2 * XSZ);
    char* WAR = wsb + 6 * FSZ + 3 * XSZ;
    unsigned short* W0p    = (unsigned short*)(WAR);
    unsigned short* W1p    = (unsigned short*)(WAR + 163840);
    unsigned short* Wqp    = (unsigned short*)(WAR + 491520);
    unsigned short* Wkvp   = (unsigned short*)(WAR + 524288);
    unsigned short* Wpoolp = (unsigned short*)(WAR + 557056);
    float* b0sum = (float*)(WAR + 851968);
    float* s1a   = (float*)(WAR + 852480);
    float* t1a   = (float*)(WAR + 852992);
    // aliases (lifetimes disjoint, stream-ordered):
    unsigned short* KV0 = F0;    // live: proj -> attn
    unsigned short* KV2 = F1;    // live: proj -> attn
    unsigned short* Qb  = F2;    // live: proj -> attn
    unsigned short* P0  = G1;    // G1 dead after proj; live: attn -> expand
    unsigned short* P1  = X0;    // spans X0+X1 (dead after conv3<64>)
    unsigned short* A1p = F0;    // KV0 slot, dead after attn; live: expand -> pool

    zero_borders_kernel<<<dim3(65, 1, 9), 256, 0, stream>>>(X0, X1, X2, F0, F1, F2, G0, G1, G2);
    pack_kernel<<<dim3(80, 1, 6), 256, 0, stream>>>(
        W_conv0, W_adj, W_conv1, Wq, Wkv, W_pool, b_conv0, b_adj,
        gamma1, beta1, mean1, var1, W0p, W1p, Wqp, Wkvp, Wpoolp, b0sum, s1a, t1a);
    prep_kernel<<<dim3(128, 6), 256, 0, stream>>>(
        x0, x1, x2, gamma0, beta0, mean0, var0, X0, X1, X2);

    conv3_kernel<64, 0><<<dim3(1536), 256, 0, stream>>>(
        X0, X1, X2, W0p, b0sum, s1a, t1a, F0, F1, F2);
    conv3_kernel<128, 1><<<dim3(1536), 256, 0, stream>>>(
        F0, F1, F2, W1p, b_conv1, nullptr, nullptr, G0, G1, G2);

    proj_kernel<<<dim3(2, 130, 6), 256, 0, stream>>>(
        G0, G1, G2, Wqp, Wkvp, bq, bkv, KV0, KV2, Qb);
    kv_border_kernel<<<dim3(65), 256, 0, stream>>>(KV0, KV2, bkv);

    attn_kernel<<<dim3(2048), 128, 0, stream>>>(Qb, KV0, KV2, P0, P1);

    zero_one_kernel<<<dim3(65), 256, 0, stream>>>(A1p);
    expand_kernel<<<dim3(128, 2), 256, 0, stream>>>(P0, P1, A1p, pass);

    pool_kernel<<<dim3(768), 256, 0, stream>>>(G0, A1p, G2, Wpoolp, b_pool, out);
}